// Round 5
// baseline (5092.613 us; speedup 1.0000x reference)
//
#include <hip/hip_runtime.h>
#include <hip/hip_bf16.h>
#include <math.h>

typedef __hip_bfloat16 bf16;
typedef __attribute__((ext_vector_type(8))) short short8b;
typedef __attribute__((ext_vector_type(8))) __bf16 bf16x8;
typedef __attribute__((ext_vector_type(4))) float f32x4;

#define SCALE_F 0.04419417382415922f  // 1/sqrt(512)

// ---- MFMA wrapper tolerant of either builtin signature (v8i16 or v8bf16) ----
template <typename V>
static __device__ inline auto mfma_try(V a, V b, f32x4 c, int)
    -> decltype(__builtin_amdgcn_mfma_f32_16x16x32_bf16(a, b, c, 0, 0, 0)) {
  return __builtin_amdgcn_mfma_f32_16x16x32_bf16(a, b, c, 0, 0, 0);
}
template <typename V>
static __device__ inline auto mfma_try(V a, V b, f32x4 c, long)
    -> decltype(__builtin_amdgcn_mfma_f32_16x16x32_bf16(
        __builtin_bit_cast(bf16x8, a), __builtin_bit_cast(bf16x8, b), c, 0, 0, 0)) {
  return __builtin_amdgcn_mfma_f32_16x16x32_bf16(
      __builtin_bit_cast(bf16x8, a), __builtin_bit_cast(bf16x8, b), c, 0, 0, 0);
}
static __device__ inline f32x4 MFMA(short8b a, short8b b, f32x4 c) {
  return mfma_try(a, b, c, 0);
}

static __device__ inline short8b ldb8(const bf16* p) {
  return *reinterpret_cast<const short8b*>(p);
}
static __device__ inline float b2f(bf16 v) { return __bfloat162float(v); }
static __device__ inline bf16 f2b(float v) { return __float2bfloat16(v); }
static __device__ inline float s2f(short s) {
  unsigned u = ((unsigned)(unsigned short)s) << 16;
  return __builtin_bit_cast(float, u);
}
static __device__ inline unsigned pack2(float lo, float hi) {
  const unsigned a = (unsigned)__builtin_bit_cast(unsigned short, f2b(lo));
  const unsigned b = (unsigned)__builtin_bit_cast(unsigned short, f2b(hi));
  return a | (b << 16);
}
static __device__ inline float sigm(float x) { return 1.f / (1.f + expf(-x)); }

// write-through stores: bypass L1/L2, land at the LLC (device coherence
// point) -> cross-XCD visible without any cache-wide fence ops.
static __device__ inline void st2_wt(bf16* p, float v) {
  unsigned ud = (unsigned)__builtin_bit_cast(unsigned short, f2b(v));
  asm volatile("global_store_short %0, %1, off sc0 sc1" ::"v"(p), "v"(ud)
               : "memory");
}
static __device__ inline void st4_wt(bf16* p, float lo, float hi) {
  unsigned ud = pack2(lo, hi);
  asm volatile("global_store_dword %0, %1, off sc0 sc1" ::"v"(p), "v"(ud)
               : "memory");
}

static __device__ inline void st_flag(unsigned* p, unsigned v) {
  asm volatile("global_store_dword %0, %1, off sc0 sc1" ::"v"(p), "v"(v)
               : "memory");
}
static __device__ inline unsigned ld_flag(const unsigned* p) {
  unsigned v;
  asm volatile("global_load_dword %0, %1, off sc0 sc1\n\ts_waitcnt vmcnt(0)"
               : "=v"(v)
               : "v"(p)
               : "memory");
  return v;
}

// ---- 8-block per-direction flag barrier ----
static __device__ inline void gbar8(unsigned* flg, unsigned ep, int bd, int tid) {
  asm volatile("s_waitcnt vmcnt(0)" ::: "memory");
  __syncthreads();
  if (tid < 64) {
    unsigned* row = flg + (size_t)ep * 64;
    if (tid == 0) st_flag(row + bd, 1u);
    while (true) {
      const unsigned v = ld_flag(row + (tid & 7));
      if (__ballot(v != 0) == ~0ull) break;
      __builtin_amdgcn_s_sleep(1);
    }
  }
  __syncthreads();
}

// =======================  generic MFMA GEMM  =======================
// C[M,N] = A[M,K] @ B[N,K]^T (+bias), A/B bf16 row-major K-contig, fp32 accum.
template <typename OutT, bool HAS_BIAS>
__global__ __launch_bounds__(256) void gemm_k(
    const bf16* __restrict__ A, const bf16* __restrict__ Bw,
    OutT* __restrict__ C, const float* __restrict__ bias,
    int M, int N, int K) {
  const int lane = threadIdx.x & 63;
  const int wid = threadIdx.x >> 6;
  const int m0 = blockIdx.y * 128 + (wid >> 1) * 64;
  const int n0 = blockIdx.x * 128 + (wid & 1) * 64;
  const int lr = lane & 15;
  const int lk = (lane >> 4) * 8;
  f32x4 acc[4][4];
#pragma unroll
  for (int i = 0; i < 4; ++i)
#pragma unroll
    for (int j = 0; j < 4; ++j) acc[i][j] = (f32x4){0.f, 0.f, 0.f, 0.f};
  const bf16* Ap = A + (size_t)(m0 + lr) * K + lk;
  const bf16* Bp = Bw + (size_t)(n0 + lr) * K + lk;
  for (int k0 = 0; k0 < K; k0 += 32) {
    short8b av[4], bv[4];
#pragma unroll
    for (int i = 0; i < 4; ++i) av[i] = ldb8(Ap + (size_t)i * 16 * K + k0);
#pragma unroll
    for (int i = 0; i < 4; ++i) bv[i] = ldb8(Bp + (size_t)i * 16 * K + k0);
#pragma unroll
    for (int mi = 0; mi < 4; ++mi)
#pragma unroll
      for (int ni = 0; ni < 4; ++ni)
        acc[mi][ni] = MFMA(av[mi], bv[ni], acc[mi][ni]);
  }
  const int rb = (lane >> 4) * 4;
#pragma unroll
  for (int mi = 0; mi < 4; ++mi) {
#pragma unroll
    for (int r = 0; r < 4; ++r) {
      const int row = m0 + mi * 16 + rb + r;
#pragma unroll
      for (int ni = 0; ni < 4; ++ni) {
        const int col = n0 + ni * 16 + lr;
        float v = acc[mi][ni][r];
        if (HAS_BIAS) v += bias[col];
        if constexpr (sizeof(OutT) == 2) {
          C[(size_t)row * N + col] = f2b(v);
        } else {
          C[(size_t)row * N + col] = v;
        }
      }
    }
  }
}

// =======================  prep kernels  =======================
__global__ void k_xg(const float* __restrict__ emb, const int* __restrict__ trg,
                     bf16* __restrict__ xg) {
  const int i = blockIdx.x * 256 + threadIdx.x;   // 2048*512 exact
  const int r = i >> 9, e = i & 511;
  const int t = r >> 5, b = r & 31;
  const int tok = trg[b * 64 + t];
  xg[i] = f2b(emb[(size_t)tok * 512 + e]);
}

__global__ void k_srcb(const float* __restrict__ s, bf16* __restrict__ d) {
  const int i = blockIdx.x * 256 + threadIdx.x;   // 2048*1024 exact
  d[i] = f2b(s[i]);
}

__global__ void k_fcw(const float* __restrict__ s, bf16* __restrict__ d) {
  const size_t stride = (size_t)gridDim.x * blockDim.x;
  for (size_t i = blockIdx.x * (size_t)blockDim.x + threadIdx.x;
       i < (size_t)32000 * 1024; i += stride)
    d[i] = f2b(s[i]);
}

__global__ void k_wpack(const float* __restrict__ fWih, const float* __restrict__ fWhh,
                        const float* __restrict__ bWih, const float* __restrict__ bWhh,
                        const float* __restrict__ fattW, const float* __restrict__ battW,
                        const float* __restrict__ bahW, const float* __restrict__ fahW,
                        bf16* Wxf, bf16* Wxb, bf16* Wrecf, bf16* Wrecb,
                        bf16* attWtf, bf16* attWtb, bf16* ahW2f, bf16* ahW2b,
                        bf16* Wh1f, bf16* Wh1b) {
  const int stride = gridDim.x * blockDim.x;
  const int i0 = blockIdx.x * blockDim.x + threadIdx.x;
  for (int i = i0; i < 2048 * 512; i += stride) {        // Wih x-slice
    const int gc = i >> 9, k = i & 511;
    Wxf[i] = f2b(fWih[(size_t)gc * 1024 + k]);
    Wxb[i] = f2b(bWih[(size_t)gc * 1024 + k]);
  }
  for (int i = i0; i < 2048 * 1024; i += stride) {       // [Wih_h | Whh]
    const int gc = i >> 10, k = i & 1023;
    float vf, vb;
    if (k < 512) { vf = fWih[(size_t)gc * 1024 + 512 + k]; vb = bWih[(size_t)gc * 1024 + 512 + k]; }
    else         { vf = fWhh[(size_t)gc * 512 + k - 512]; vb = bWhh[(size_t)gc * 512 + k - 512]; }
    Wrecf[i] = f2b(vf); Wrecb[i] = f2b(vb);
  }
  for (int i = i0; i < 512 * 1024; i += stride) {        // attW transpose
    const int j = i >> 10, d = i & 1023;
    attWtf[i] = f2b(fattW[(size_t)d * 512 + j]);
    attWtb[i] = f2b(battW[(size_t)d * 512 + j]);
  }
  for (int i = i0; i < 512 * 1024; i += stride) {        // ah_W ct-slice (swapped: fwd uses bah)
    const int o = i >> 10, d = i & 1023;
    ahW2f[i] = f2b(bahW[(size_t)o * 1536 + 512 + d]);
    ahW2b[i] = f2b(fahW[(size_t)o * 1536 + 512 + d]);
  }
  for (int i = i0; i < 512 * 512; i += stride) {         // ah_W h-slice bf16 [o][k]
    const int o = i >> 9, k = i & 511;
    Wh1f[i] = f2b(bahW[(size_t)o * 1536 + k]);
    Wh1b[i] = f2b(fahW[(size_t)o * 1536 + k]);
  }
}

__global__ void k_c0(const float* __restrict__ src, const float* __restrict__ fb,
                     const float* __restrict__ bb, float* __restrict__ c0f,
                     float* __restrict__ c0b) {
  const int r = blockIdx.x;
  const int tid = threadIdx.x;
  float pf = 0.f, pb = 0.f;
  for (int d = tid; d < 1024; d += 256) {
    const float s = src[(size_t)r * 1024 + d];
    pf += s * fb[d];
    pb += s * bb[d];
  }
#pragma unroll
  for (int d = 1; d < 64; d <<= 1) { pf += __shfl_xor(pf, d); pb += __shfl_xor(pb, d); }
  __shared__ float rf[4], rb2[4];
  if ((tid & 63) == 0) { rf[tid >> 6] = pf; rb2[tid >> 6] = pb; }
  __syncthreads();
  if (tid == 0) {
    c0f[r] = (rf[0] + rf[1] + rf[2] + rf[3]) * SCALE_F;
    c0b[r] = (rb2[0] + rb2[1] + rb2[2] + rb2[3]) * SCALE_F;
  }
}

// rolling state buffers per dir: hh[65][32][512], hb[65][32][512] bf16
__global__ void k_init(const float* __restrict__ feed, const float* __restrict__ hid,
                       bf16* hh0, bf16* hh1, bf16* hb0, bf16* hb1,
                       float* cst0, float* cst1) {
  const int i = blockIdx.x * 256 + threadIdx.x;   // 32*512 exact
  const int b = i >> 9, k = i & 511;
  hh0[i] = f2b(feed[k]);
  hh1[i] = f2b(feed[512 + k]);
  hb0[i] = f2b(hid[k]);
  hb1[i] = f2b(hid[1024 + k]);
  cst0[k * 32 + b] = hid[512 + k];
  cst1[k * 32 + b] = hid[1536 + k];
}

// =======================  sequential scan  =======================
// 16 blocks x 1024 threads. dir = blk>>3, bd = blk&7.
// 16 waves: grp = wv>>2 (0..3), sub = wv&3.
// Wave (grp,sub): PhaseA -> gate=sub, j-slice g=bd*4+grp (global 0..31).
// PhaseB/C -> batch g (and U o-slice g for sub 0).
struct ScanP {
  const bf16* Wrec[2]; const bf16* Xp[2]; const bf16* Af[2]; const bf16* Bm[2];
  const bf16* Wh1[2]; const float* bih[2]; const float* bhh[2];
  const float* c0[2]; const float* ahb[2]; const float* mask;
  bf16* hh[2]; bf16* hb[2]; bf16* U[2]; float* cst[2]; bf16* hcat; unsigned* flags;
};

__global__ __launch_bounds__(1024) void scan_k(ScanP P) {
  const int blk = blockIdx.x;     // 16 blocks
  const int dir = blk >> 3;
  const int bd = blk & 7;
  const int tid = threadIdx.x;
  const int lane = tid & 63;
  const int wv = tid >> 6;
  const int grp = wv >> 2;
  const int sub = wv & 3;

  const bf16* __restrict__ Wrec = P.Wrec[dir];
  const bf16* __restrict__ Xp = P.Xp[dir];
  const bf16* __restrict__ Af = P.Af[dir];
  const bf16* __restrict__ Bm = P.Bm[dir];
  const bf16* __restrict__ Wh1 = P.Wh1[dir];
  const float* __restrict__ bihp = P.bih[dir];
  const float* __restrict__ bhhp = P.bhh[dir];
  const float* __restrict__ c0v = P.c0[dir];
  const float* __restrict__ ahbp = P.ahb[dir];
  bf16* __restrict__ hhB = P.hh[dir];
  bf16* __restrict__ hbB = P.hb[dir];
  bf16* __restrict__ Ubuf = P.U[dir];
  float* __restrict__ cst = P.cst[dir];
  unsigned* __restrict__ flg = P.flags + (size_t)dir * 192 * 64;

  __shared__ float gl[4][4][16][33];    // [gate][grp][j-in-slice][batch]
  __shared__ float h_lds[4][512];
  __shared__ float w_part[4][2][64];
  __shared__ float p_lds[4][64];

  unsigned ep = 0;
  const int lr16 = lane & 15;
  const int kb = lane >> 4;
  const int koff = kb * 8;
  const int g = bd * 4 + grp;           // global slice / batch id for this wave-group

  for (int t = 0; t < 64; ++t) {
    const bf16* hhR = hhB + (size_t)t * 32 * 512;        // hhat_{t-1}
    bf16* hhW = hhB + (size_t)(t + 1) * 32 * 512;
    const bf16* hbR = hbB + (size_t)t * 32 * 512;        // h_{t-1}
    bf16* hbW = hbB + (size_t)(t + 1) * 32 * 512;        // h_t

    // ---------- Phase A: gate MFMA (wave = gate sub, j-slice g) ----------
    {
      const int gate = sub;
      const int gc = gate * 512 + g * 16 + lr16;
      const bf16* Brow = Wrec + (size_t)gc * 1024;
      const bf16* A0h = hhR + (size_t)lr16 * 512;
      const bf16* A1h = hhR + (size_t)(lr16 + 16) * 512;
      const bf16* A0g = hbR + (size_t)lr16 * 512;
      const bf16* A1g = hbR + (size_t)(lr16 + 16) * 512;
      f32x4 ac0 = (f32x4){0.f, 0.f, 0.f, 0.f};
      f32x4 ac1 = (f32x4){0.f, 0.f, 0.f, 0.f};
#pragma unroll
      for (int ks = 0; ks < 16; ++ks) {
        const int k = ks * 32 + koff;
        const short8b bh = ldb8(Brow + 512 + k);     // Whh part (vs h)
        ac0 = MFMA(ldb8(A0g + k), bh, ac0);
        ac1 = MFMA(ldb8(A1g + k), bh, ac1);
        const short8b bx = ldb8(Brow + k);           // Wih_h part (vs hhat)
        ac0 = MFMA(ldb8(A0h + k), bx, ac0);
        ac1 = MFMA(ldb8(A1h + k), bx, ac1);
      }
      const int tcol = dir ? (63 - t) : t;
      const float bsum = bihp[gc] + bhhp[gc];
      const bf16* xpc = Xp + (size_t)gc * 2048 + tcol * 32;
#pragma unroll
      for (int r = 0; r < 4; ++r) {
        const int brow = kb * 4 + r;   // D: row=(lane>>4)*4+reg (batch), col=lane&15
        gl[gate][grp][lr16][brow] = ac0[r] + b2f(xpc[brow]) + bsum;
        gl[gate][grp][lr16][brow + 16] = ac1[r] + b2f(xpc[brow + 16]) + bsum;
      }
    }
    __syncthreads();
    {
      // LSTM cell: thread = (b = tid>>5, j-pair j2 = tid&31), 2048 cells total
      const int b = tid >> 5;
      const int j2 = tid & 31;
      const float m = dir ? P.mask[b * 64 + (63 - t)] : 1.f;
      float hn2[2];
#pragma unroll
      for (int u = 0; u < 2; ++u) {
        const int jl = j2 * 2 + u;
        const int jq = jl >> 4, jr = jl & 15;
        const float gi = gl[0][jq][jr][b];
        const float gf = gl[1][jq][jr][b];
        const float gg = gl[2][jq][jr][b];
        const float go = gl[3][jq][jr][b];
        const int j = bd * 64 + jl;
        float cn = sigm(gf) * cst[j * 32 + b] + sigm(gi) * tanhf(gg);
        float hn = sigm(go) * tanhf(cn);
        hn *= m; cn *= m;
        cst[j * 32 + b] = cn;                        // block-private, cached
        hn2[u] = hn;
      }
      st4_wt(hbW + (size_t)b * 512 + bd * 64 + j2 * 2, hn2[0], hn2[1]);
    }
    gbar8(flg, ep++, bd, tid);

    // ---------- Phase B: U (sub 0) | attention (subs 1-3), per wave-group ----------
    if (sub == 0) {
      // U[b, o-slice g] = Wh1[o-slice,:] . h_t[b,:]
      const bf16* Brow = Wh1 + (size_t)(g * 16 + lr16) * 512;
      const bf16* A0 = hbW + (size_t)lr16 * 512;
      const bf16* A1 = hbW + (size_t)(lr16 + 16) * 512;
      f32x4 u0 = (f32x4){0.f, 0.f, 0.f, 0.f};
      f32x4 u1 = (f32x4){0.f, 0.f, 0.f, 0.f};
#pragma unroll
      for (int ks = 0; ks < 16; ++ks) {
        const int k = ks * 32 + koff;
        const short8b bv = ldb8(Brow + k);
        u0 = MFMA(ldb8(A0 + k), bv, u0);
        u1 = MFMA(ldb8(A1 + k), bv, u1);
      }
      bf16* Uw = Ubuf + (size_t)t * 32 * 512;
      const int o = g * 16 + lr16;
#pragma unroll
      for (int r = 0; r < 4; ++r) {
        const int b0 = kb * 4 + r;
        st2_wt(Uw + (size_t)b0 * 512 + o, u0[r]);
        st2_wt(Uw + (size_t)(b0 + 16) * 512 + o, u1[r]);
      }
    } else if (sub == 1) {
      const short8b v = ldb8(hbW + (size_t)g * 512 + lane * 8);  // h_t[g,:] -> LDS
#pragma unroll
      for (int e = 0; e < 8; ++e) h_lds[grp][lane * 8 + e] = s2f(v[e]);
    }
    __syncthreads();
    if (sub == 1 || sub == 2) {
      const int q = sub - 1;
      const bf16* arow = Af + (size_t)(g * 64 + lane) * 512 + q * 256;
      float part = 0.f;
#pragma unroll 4
      for (int k8 = 0; k8 < 256; k8 += 8) {
        const short8b v = ldb8(arow + k8);
#pragma unroll
        for (int e = 0; e < 8; ++e) part += h_lds[grp][q * 256 + k8 + e] * s2f(v[e]);
      }
      w_part[grp][q][lane] = part;
    }
    __syncthreads();
    if (sub == 3) {
      const float v = (w_part[grp][0][lane] + w_part[grp][1][lane]) * SCALE_F +
                      c0v[g * 64 + lane];
      float mx = v;
#pragma unroll
      for (int d = 1; d < 64; d <<= 1) mx = fmaxf(mx, __shfl_xor(mx, d));
      const float e = expf(v - mx);
      float sm = e;
#pragma unroll
      for (int d = 1; d < 64; d <<= 1) sm += __shfl_xor(sm, d);
      p_lds[grp][lane] = e / sm;
    }
    __syncthreads();
    float a2[2];
    {
      // acc2 = ahb + p . Bm : group threads (256) cover 512 o's, pair per thread
      const int tg = sub * 64 + lane;
      const int o2 = tg * 2;
      a2[0] = ahbp[o2];
      a2[1] = ahbp[o2 + 1];
      const bf16* bmc = Bm + (size_t)(g * 64) * 512 + o2;
#pragma unroll 4
      for (int s2 = 0; s2 < 64; ++s2) {
        const unsigned uv = *reinterpret_cast<const unsigned*>(bmc + (size_t)s2 * 512);
        const float p = p_lds[grp][s2];
        a2[0] += p * s2f((short)(uv & 0xffffu));
        a2[1] += p * s2f((short)(uv >> 16));
      }
    }
    gbar8(flg, ep++, bd, tid);

    // ---------- Phase C: hhat = tanh(U + acc2), batch g ----------
    {
      const int tg = sub * 64 + lane;
      const int o2 = tg * 2;
      const unsigned uu =
          *reinterpret_cast<const unsigned*>(Ubuf + ((size_t)t * 32 + g) * 512 + o2);
      const float h0 = tanhf(a2[0] + s2f((short)(uu & 0xffffu)));
      const float h1 = tanhf(a2[1] + s2f((short)(uu >> 16)));
      st4_wt(hhW + (size_t)g * 512 + o2, h0, h1);
      const unsigned hp = pack2(h0, h1);
      if (dir == 0) {
        *reinterpret_cast<unsigned*>(P.hcat + (size_t)(g * 64 + t) * 1024 + o2) = hp;
      } else if (t >= 2) {
        *reinterpret_cast<unsigned*>(P.hcat + (size_t)(g * 64 + t - 2) * 1024 + 512 + o2) = hp;
      }
    }
    gbar8(flg, ep++, bd, tid);
  }
}

// =======================  host  =======================
extern "C" void kernel_launch(void* const* d_in, const int* in_sizes, int n_in,
                              void* d_out, int out_size, void* d_ws, size_t ws_size,
                              hipStream_t stream) {
  (void)in_sizes; (void)n_in; (void)out_size; (void)ws_size;
  const float* src  = (const float*)d_in[0];
  const int*   trg  = (const int*)d_in[1];
  const float* mask = (const float*)d_in[2];
  const float* emb  = (const float*)d_in[3];
  const float* fWih = (const float*)d_in[4];
  const float* fWhh = (const float*)d_in[5];
  const float* fbih = (const float*)d_in[6];
  const float* fbhh = (const float*)d_in[7];
  const float* bWih = (const float*)d_in[8];
  const float* bWhh = (const float*)d_in[9];
  const float* bbih = (const float*)d_in[10];
  const float* bbhh = (const float*)d_in[11];
  const float* fattW = (const float*)d_in[12];
  const float* fattb = (const float*)d_in[13];
  const float* battW = (const float*)d_in[14];
  const float* battb = (const float*)d_in[15];
  const float* fahW = (const float*)d_in[16];
  const float* fahb = (const float*)d_in[17];
  const float* bahW = (const float*)d_in[18];
  const float* bahb = (const float*)d_in[19];
  const float* fcW  = (const float*)d_in[20];
  const float* fcb  = (const float*)d_in[21];
  const float* feed = (const float*)d_in[22];
  const float* hid  = (const float*)d_in[23];

  char* wsp = (char*)d_ws;
  size_t off = 0;
  auto alloc = [&](size_t bytes) -> void* {
    void* p = wsp + off;
    off += (bytes + 255) & ~(size_t)255;
    return p;
  };
  unsigned* flags = (unsigned*)alloc((size_t)2 * 192 * 64 * 4);
  bf16* hcat = (bf16*)alloc((size_t)2048 * 1024 * 2);
  const size_t zero_bytes = off;                 // flags + hcat zeroed per launch
  bf16* xg    = (bf16*)alloc((size_t)2048 * 512 * 2);
  bf16* srcb  = (bf16*)alloc((size_t)2048 * 1024 * 2);
  bf16* fcWb  = (bf16*)alloc((size_t)32000 * 1024 * 2);
  bf16* Wxf   = (bf16*)alloc((size_t)2048 * 512 * 2);
  bf16* Wxb   = (bf16*)alloc((size_t)2048 * 512 * 2);
  bf16* Wrecf = (bf16*)alloc((size_t)2048 * 1024 * 2);
  bf16* Wrecb = (bf16*)alloc((size_t)2048 * 1024 * 2);
  bf16* attWtf = (bf16*)alloc((size_t)512 * 1024 * 2);
  bf16* attWtb = (bf16*)alloc((size_t)512 * 1024 * 2);
  bf16* ahW2f = (bf16*)alloc((size_t)512 * 1024 * 2);
  bf16* ahW2b = (bf16*)alloc((size_t)512 * 1024 * 2);
  bf16* Wh1f  = (bf16*)alloc((size_t)512 * 512 * 2);
  bf16* Wh1b  = (bf16*)alloc((size_t)512 * 512 * 2);
  bf16* Xpf   = (bf16*)alloc((size_t)2048 * 2048 * 2);
  bf16* Xpb   = (bf16*)alloc((size_t)2048 * 2048 * 2);
  bf16* Aff   = (bf16*)alloc((size_t)2048 * 512 * 2);
  bf16* Afb   = (bf16*)alloc((size_t)2048 * 512 * 2);
  bf16* Bmf   = (bf16*)alloc((size_t)2048 * 512 * 2);
  bf16* Bmb   = (bf16*)alloc((size_t)2048 * 512 * 2);
  float* c0f  = (float*)alloc(2048 * 4);
  float* c0b  = (float*)alloc(2048 * 4);
  bf16* hh0   = (bf16*)alloc((size_t)65 * 32 * 512 * 2);
  bf16* hh1   = (bf16*)alloc((size_t)65 * 32 * 512 * 2);
  bf16* hb0   = (bf16*)alloc((size_t)65 * 32 * 512 * 2);
  bf16* hb1   = (bf16*)alloc((size_t)65 * 32 * 512 * 2);
  bf16* Uf    = (bf16*)alloc((size_t)64 * 32 * 512 * 2);
  bf16* Ub    = (bf16*)alloc((size_t)64 * 32 * 512 * 2);
  float* cst0 = (float*)alloc((size_t)512 * 32 * 4);
  float* cst1 = (float*)alloc((size_t)512 * 32 * 4);

  hipMemsetAsync(d_ws, 0, zero_bytes, stream);

  k_xg<<<4096, 256, 0, stream>>>(emb, trg, xg);
  k_srcb<<<8192, 256, 0, stream>>>(src, srcb);
  k_fcw<<<8192, 256, 0, stream>>>(fcW, fcWb);
  k_wpack<<<2048, 256, 0, stream>>>(fWih, fWhh, bWih, bWhh, fattW, battW, bahW, fahW,
                                    Wxf, Wxb, Wrecf, Wrecb, attWtf, attWtb, ahW2f, ahW2b,
                                    Wh1f, Wh1b);
  k_c0<<<2048, 256, 0, stream>>>(src, fattb, battb, c0f, c0b);
  k_init<<<64, 256, 0, stream>>>(feed, hid, hh0, hh1, hb0, hb1, cst0, cst1);

  // Xp[gc][r] = (x @ Wih_x^T)^T  (gc-major so scan reads are b-coalesced)
  gemm_k<bf16, false><<<dim3(16, 16), 256, 0, stream>>>(Wxf, xg, Xpf, nullptr, 2048, 2048, 512);
  gemm_k<bf16, false><<<dim3(16, 16), 256, 0, stream>>>(Wxb, xg, Xpb, nullptr, 2048, 2048, 512);
  // A[r][j] = src @ attW ;  Bm[r][o] = src @ ahW_ct^T
  gemm_k<bf16, false><<<dim3(4, 16), 256, 0, stream>>>(srcb, attWtf, Aff, nullptr, 2048, 512, 1024);
  gemm_k<bf16, false><<<dim3(4, 16), 256, 0, stream>>>(srcb, attWtb, Afb, nullptr, 2048, 512, 1024);
  gemm_k<bf16, false><<<dim3(4, 16), 256, 0, stream>>>(srcb, ahW2f, Bmf, nullptr, 2048, 512, 1024);
  gemm_k<bf16, false><<<dim3(4, 16), 256, 0, stream>>>(srcb, ahW2b, Bmb, nullptr, 2048, 512, 1024);

  ScanP sp;
  sp.Wrec[0] = Wrecf; sp.Wrec[1] = Wrecb;
  sp.Xp[0] = Xpf;     sp.Xp[1] = Xpb;
  sp.Af[0] = Aff;     sp.Af[1] = Afb;
  sp.Bm[0] = Bmf;     sp.Bm[1] = Bmb;
  sp.Wh1[0] = Wh1f;   sp.Wh1[1] = Wh1b;
  sp.bih[0] = fbih;   sp.bih[1] = bbih;
  sp.bhh[0] = fbhh;   sp.bhh[1] = bbhh;
  sp.c0[0] = c0f;     sp.c0[1] = c0b;
  sp.ahb[0] = bahb;   sp.ahb[1] = fahb;   // att_hidden weights are swapped in the reference
  sp.mask = mask;
  sp.hh[0] = hh0;     sp.hh[1] = hh1;
  sp.hb[0] = hb0;     sp.hb[1] = hb1;
  sp.U[0] = Uf;       sp.U[1] = Ub;
  sp.cst[0] = cst0;   sp.cst[1] = cst1;
  sp.hcat = hcat;     sp.flags = flags;
  scan_k<<<16, 1024, 0, stream>>>(sp);

  // logits[b*64+t][v] = hcat @ fcW^T + fcb
  gemm_k<float, true><<<dim3(250, 16), 256, 0, stream>>>(hcat, fcWb, (float*)d_out, fcb,
                                                         2048, 32000, 1024);
}

// Round 6
// 2891.938 us; speedup vs baseline: 1.7610x; 1.7610x over previous
//
#include <hip/hip_runtime.h>
#include <hip/hip_bf16.h>
#include <math.h>

typedef __hip_bfloat16 bf16;
typedef __attribute__((ext_vector_type(8))) short short8b;
typedef __attribute__((ext_vector_type(8))) __bf16 bf16x8;
typedef __attribute__((ext_vector_type(4))) float f32x4;

#define SCALE_F 0.04419417382415922f  // 1/sqrt(512)

// ---- MFMA wrapper tolerant of either builtin signature (v8i16 or v8bf16) ----
template <typename V>
static __device__ inline auto mfma_try(V a, V b, f32x4 c, int)
    -> decltype(__builtin_amdgcn_mfma_f32_16x16x32_bf16(a, b, c, 0, 0, 0)) {
  return __builtin_amdgcn_mfma_f32_16x16x32_bf16(a, b, c, 0, 0, 0);
}
template <typename V>
static __device__ inline auto mfma_try(V a, V b, f32x4 c, long)
    -> decltype(__builtin_amdgcn_mfma_f32_16x16x32_bf16(
        __builtin_bit_cast(bf16x8, a), __builtin_bit_cast(bf16x8, b), c, 0, 0, 0)) {
  return __builtin_amdgcn_mfma_f32_16x16x32_bf16(
      __builtin_bit_cast(bf16x8, a), __builtin_bit_cast(bf16x8, b), c, 0, 0, 0);
}
static __device__ inline f32x4 MFMA(short8b a, short8b b, f32x4 c) {
  return mfma_try(a, b, c, 0);
}

static __device__ inline short8b ldb8(const bf16* p) {
  return *reinterpret_cast<const short8b*>(p);
}
static __device__ inline float b2f(bf16 v) { return __bfloat162float(v); }
static __device__ inline bf16 f2b(float v) { return __float2bfloat16(v); }
static __device__ inline float s2f(short s) {
  unsigned u = ((unsigned)(unsigned short)s) << 16;
  return __builtin_bit_cast(float, u);
}
static __device__ inline unsigned pack2(float lo, float hi) {
  const unsigned a = (unsigned)__builtin_bit_cast(unsigned short, f2b(lo));
  const unsigned b = (unsigned)__builtin_bit_cast(unsigned short, f2b(hi));
  return a | (b << 16);
}
static __device__ inline float sigm(float x) { return 1.f / (1.f + expf(-x)); }

// XCD-LOCAL protocol: workers of one direction all live on ONE XCD and share
// its L2. State stores are PLAIN (ACK at local L2); state reads are PLAIN
// (per-step-unique rolling addresses -> no stale L1 line can exist; L1 miss
// -> shared L2 hit). Only the barrier flags use sc0 sc1 (tiny traffic).
static __device__ inline void st2p(bf16* p, float v) { *p = f2b(v); }
static __device__ inline void st4p(bf16* p, float lo, float hi) {
  *reinterpret_cast<unsigned*>(p) = pack2(lo, hi);
}

static __device__ inline void st_flag(unsigned* p, unsigned v) {
  asm volatile("global_store_dword %0, %1, off sc0 sc1" ::"v"(p), "v"(v)
               : "memory");
}
static __device__ inline unsigned ld_flag(const unsigned* p) {
  unsigned v;
  asm volatile("global_load_dword %0, %1, off sc0 sc1\n\ts_waitcnt vmcnt(0)"
               : "=v"(v)
               : "v"(p)
               : "memory");
  return v;
}

// ---- XCD-local flag barrier over 32 worker blocks of one direction ----
// vmcnt(0) drains this wave's plain stores to the XCD's L2; flag row is
// per-phase-unique. Poll is bounded for hang-safety (never triggers in
// practice; claim guarantees 32 workers).
static __device__ inline void xbar(unsigned* flg, unsigned ep, int g, int tid) {
  asm volatile("s_waitcnt vmcnt(0)" ::: "memory");
  __syncthreads();
  if (tid < 64) {
    unsigned* row = flg + (size_t)ep * 64;
    if (tid == 0) st_flag(row + g, 1u);
    int guard = 0;
    while (guard++ < (1 << 22)) {
      const unsigned v = ld_flag(row + (tid & 31));
      if (__ballot(v != 0) == ~0ull) break;
      __builtin_amdgcn_s_sleep(1);
    }
  }
  __syncthreads();
}

// =======================  generic MFMA GEMM  =======================
// C[M,N] = A[M,K] @ B[N,K]^T (+bias), A/B bf16 row-major K-contig, fp32 accum.
template <typename OutT, bool HAS_BIAS>
__global__ __launch_bounds__(256) void gemm_k(
    const bf16* __restrict__ A, const bf16* __restrict__ Bw,
    OutT* __restrict__ C, const float* __restrict__ bias,
    int M, int N, int K) {
  const int lane = threadIdx.x & 63;
  const int wid = threadIdx.x >> 6;
  const int m0 = blockIdx.y * 128 + (wid >> 1) * 64;
  const int n0 = blockIdx.x * 128 + (wid & 1) * 64;
  const int lr = lane & 15;
  const int lk = (lane >> 4) * 8;
  f32x4 acc[4][4];
#pragma unroll
  for (int i = 0; i < 4; ++i)
#pragma unroll
    for (int j = 0; j < 4; ++j) acc[i][j] = (f32x4){0.f, 0.f, 0.f, 0.f};
  const bf16* Ap = A + (size_t)(m0 + lr) * K + lk;
  const bf16* Bp = Bw + (size_t)(n0 + lr) * K + lk;
  for (int k0 = 0; k0 < K; k0 += 32) {
    short8b av[4], bv[4];
#pragma unroll
    for (int i = 0; i < 4; ++i) av[i] = ldb8(Ap + (size_t)i * 16 * K + k0);
#pragma unroll
    for (int i = 0; i < 4; ++i) bv[i] = ldb8(Bp + (size_t)i * 16 * K + k0);
#pragma unroll
    for (int mi = 0; mi < 4; ++mi)
#pragma unroll
      for (int ni = 0; ni < 4; ++ni)
        acc[mi][ni] = MFMA(av[mi], bv[ni], acc[mi][ni]);
  }
  const int rb = (lane >> 4) * 4;
#pragma unroll
  for (int mi = 0; mi < 4; ++mi) {
#pragma unroll
    for (int r = 0; r < 4; ++r) {
      const int row = m0 + mi * 16 + rb + r;
#pragma unroll
      for (int ni = 0; ni < 4; ++ni) {
        const int col = n0 + ni * 16 + lr;
        float v = acc[mi][ni][r];
        if (HAS_BIAS) v += bias[col];
        if constexpr (sizeof(OutT) == 2) {
          C[(size_t)row * N + col] = f2b(v);
        } else {
          C[(size_t)row * N + col] = v;
        }
      }
    }
  }
}

// =======================  prep kernels  =======================
__global__ void k_xg(const float* __restrict__ emb, const int* __restrict__ trg,
                     bf16* __restrict__ xg) {
  const int i = blockIdx.x * 256 + threadIdx.x;   // 2048*512 exact
  const int r = i >> 9, e = i & 511;
  const int t = r >> 5, b = r & 31;
  const int tok = trg[b * 64 + t];
  xg[i] = f2b(emb[(size_t)tok * 512 + e]);
}

__global__ void k_srcb(const float* __restrict__ s, bf16* __restrict__ d) {
  const int i = blockIdx.x * 256 + threadIdx.x;   // 2048*1024 exact
  d[i] = f2b(s[i]);
}

__global__ void k_fcw(const float* __restrict__ s, bf16* __restrict__ d) {
  const size_t stride = (size_t)gridDim.x * blockDim.x;
  for (size_t i = blockIdx.x * (size_t)blockDim.x + threadIdx.x;
       i < (size_t)32000 * 1024; i += stride)
    d[i] = f2b(s[i]);
}

__global__ void k_wpack(const float* __restrict__ fWih, const float* __restrict__ fWhh,
                        const float* __restrict__ bWih, const float* __restrict__ bWhh,
                        const float* __restrict__ fattW, const float* __restrict__ battW,
                        const float* __restrict__ bahW, const float* __restrict__ fahW,
                        bf16* Wxf, bf16* Wxb, bf16* Wrecf, bf16* Wrecb,
                        bf16* attWtf, bf16* attWtb, bf16* ahW2f, bf16* ahW2b,
                        bf16* Wh1f, bf16* Wh1b) {
  const int stride = gridDim.x * blockDim.x;
  const int i0 = blockIdx.x * blockDim.x + threadIdx.x;
  for (int i = i0; i < 2048 * 512; i += stride) {        // Wih x-slice
    const int gc = i >> 9, k = i & 511;
    Wxf[i] = f2b(fWih[(size_t)gc * 1024 + k]);
    Wxb[i] = f2b(bWih[(size_t)gc * 1024 + k]);
  }
  for (int i = i0; i < 2048 * 1024; i += stride) {       // [Wih_h | Whh]
    const int gc = i >> 10, k = i & 1023;
    float vf, vb;
    if (k < 512) { vf = fWih[(size_t)gc * 1024 + 512 + k]; vb = bWih[(size_t)gc * 1024 + 512 + k]; }
    else         { vf = fWhh[(size_t)gc * 512 + k - 512]; vb = bWhh[(size_t)gc * 512 + k - 512]; }
    Wrecf[i] = f2b(vf); Wrecb[i] = f2b(vb);
  }
  for (int i = i0; i < 512 * 1024; i += stride) {        // attW transpose
    const int j = i >> 10, d = i & 1023;
    attWtf[i] = f2b(fattW[(size_t)d * 512 + j]);
    attWtb[i] = f2b(battW[(size_t)d * 512 + j]);
  }
  for (int i = i0; i < 512 * 1024; i += stride) {        // ah_W ct-slice (swapped: fwd uses bah)
    const int o = i >> 10, d = i & 1023;
    ahW2f[i] = f2b(bahW[(size_t)o * 1536 + 512 + d]);
    ahW2b[i] = f2b(fahW[(size_t)o * 1536 + 512 + d]);
  }
  for (int i = i0; i < 512 * 512; i += stride) {         // ah_W h-slice bf16 [o][k]
    const int o = i >> 9, k = i & 511;
    Wh1f[i] = f2b(bahW[(size_t)o * 1536 + k]);
    Wh1b[i] = f2b(fahW[(size_t)o * 1536 + k]);
  }
}

__global__ void k_c0(const float* __restrict__ src, const float* __restrict__ fb,
                     const float* __restrict__ bb, float* __restrict__ c0f,
                     float* __restrict__ c0b) {
  const int r = blockIdx.x;
  const int tid = threadIdx.x;
  float pf = 0.f, pb = 0.f;
  for (int d = tid; d < 1024; d += 256) {
    const float s = src[(size_t)r * 1024 + d];
    pf += s * fb[d];
    pb += s * bb[d];
  }
#pragma unroll
  for (int d = 1; d < 64; d <<= 1) { pf += __shfl_xor(pf, d); pb += __shfl_xor(pb, d); }
  __shared__ float rf[4], rb2[4];
  if ((tid & 63) == 0) { rf[tid >> 6] = pf; rb2[tid >> 6] = pb; }
  __syncthreads();
  if (tid == 0) {
    c0f[r] = (rf[0] + rf[1] + rf[2] + rf[3]) * SCALE_F;
    c0b[r] = (rb2[0] + rb2[1] + rb2[2] + rb2[3]) * SCALE_F;
  }
}

// rolling state buffers per dir: hh[65][32][512], hb[65][32][512] bf16
__global__ void k_init(const float* __restrict__ feed, const float* __restrict__ hid,
                       bf16* hh0, bf16* hh1, bf16* hb0, bf16* hb1,
                       float* cst0, float* cst1) {
  const int i = blockIdx.x * 256 + threadIdx.x;   // 32*512 exact
  const int b = i >> 9, k = i & 511;
  hh0[i] = f2b(feed[k]);
  hh1[i] = f2b(feed[512 + k]);
  hb0[i] = f2b(hid[k]);
  hb1[i] = f2b(hid[1024 + k]);
  cst0[k * 32 + b] = hid[512 + k];
  cst1[k * 32 + b] = hid[1536 + k];
}

// =======================  sequential scan (XCD-local)  =======================
// 1024 candidate blocks x 256 thr. Each block reads its XCD id; blocks on
// XCD 0 claim ranks for dir 0, XCD 1 for dir 1; ranks 0..31 become workers
// (j-slice g = rank in Phase A, batch g in Phase B/C), everyone else exits.
// All of a direction's state traffic stays in ONE XCD's L2.
struct ScanP {
  const bf16* Wrec[2]; const bf16* Xp[2]; const bf16* Af[2]; const bf16* Bm[2];
  const bf16* Wh1[2]; const float* bih[2]; const float* bhh[2];
  const float* c0[2]; const float* ahb[2]; const float* mask;
  bf16* hh[2]; bf16* hb[2]; bf16* U[2]; float* cst[2]; bf16* hcat;
  unsigned* flags; unsigned* claim;
};

__global__ __launch_bounds__(256) void scan_k(ScanP P) {
  __shared__ int s_dir, s_g;
  if (threadIdx.x == 0) {
    unsigned xcc;
    asm volatile("s_getreg_b32 %0, hwreg(HW_REG_XCC_ID)" : "=s"(xcc));
    xcc &= 7u;
    int rank = 1000;
    if (xcc < 2) rank = (int)atomicAdd(P.claim + xcc, 1u);
    s_dir = (int)xcc;
    s_g = rank;
  }
  __syncthreads();
  const int dir = s_dir;
  const int g = s_g;
  if (dir >= 2 || g >= 32) return;

  const int tid = threadIdx.x;
  const int lane = tid & 63;
  const int wv = tid >> 6;

  const bf16* __restrict__ Wrec = P.Wrec[dir];
  const bf16* __restrict__ Xp = P.Xp[dir];
  const bf16* __restrict__ Af = P.Af[dir];
  const bf16* __restrict__ Bm = P.Bm[dir];
  const bf16* __restrict__ Wh1 = P.Wh1[dir];
  const float* __restrict__ bihp = P.bih[dir];
  const float* __restrict__ bhhp = P.bhh[dir];
  const float* __restrict__ c0v = P.c0[dir];
  const float* __restrict__ ahbp = P.ahb[dir];
  bf16* __restrict__ hhB = P.hh[dir];
  bf16* __restrict__ hbB = P.hb[dir];
  bf16* __restrict__ Ubuf = P.U[dir];
  float* __restrict__ cst = P.cst[dir];
  unsigned* __restrict__ flg = P.flags + (size_t)dir * 192 * 64;

  __shared__ float gl[4][16][33];
  __shared__ float h_lds[512];
  __shared__ float w_part[2][64];
  __shared__ float p_lds[64];

  unsigned ep = 0;
  const int lr16 = lane & 15;
  const int kb = lane >> 4;
  const int koff = kb * 8;

  // prefetched h_{t-1} A-fragments (rows lr16, lr16+16), registers
  short8b pA0[16], pA1[16];
  {
    const bf16* A0 = hbB + (size_t)lr16 * 512;           // slot 0 = h_{-1}
    const bf16* A1 = hbB + (size_t)(lr16 + 16) * 512;
#pragma unroll
    for (int ks = 0; ks < 16; ++ks) {
      pA0[ks] = ldb8(A0 + ks * 32 + koff);
      pA1[ks] = ldb8(A1 + ks * 32 + koff);
    }
  }

  for (int t = 0; t < 64; ++t) {
    const bf16* hhR = hhB + (size_t)t * 32 * 512;        // hhat_{t-1}
    bf16* hhW = hhB + (size_t)(t + 1) * 32 * 512;
    bf16* hbW = hbB + (size_t)(t + 1) * 32 * 512;        // h_t (written below)

    // ---------- Phase A: gates (MFMA) + LSTM cell, block owns j-slice g ----------
    {
      const int gate = wv;                   // wave 0..3 -> i,f,g,o
      const int gc = gate * 512 + g * 16 + lr16;
      const bf16* Brow = Wrec + (size_t)gc * 1024;
      const bf16* A0h = hhR + (size_t)lr16 * 512;
      const bf16* A1h = hhR + (size_t)(lr16 + 16) * 512;
      f32x4 ac0 = (f32x4){0.f, 0.f, 0.f, 0.f};
      f32x4 ac1 = (f32x4){0.f, 0.f, 0.f, 0.f};
#pragma unroll
      for (int ks = 0; ks < 16; ++ks) {      // h part first (prefetched regs)
        const int k = ks * 32 + koff;
        const short8b bv = ldb8(Brow + 512 + k);
        ac0 = MFMA(pA0[ks], bv, ac0);
        ac1 = MFMA(pA1[ks], bv, ac1);
      }
#pragma unroll
      for (int ks = 0; ks < 16; ++ks) {      // hhat part (fresh loads)
        const int k = ks * 32 + koff;
        const short8b bv = ldb8(Brow + k);
        ac0 = MFMA(ldb8(A0h + k), bv, ac0);
        ac1 = MFMA(ldb8(A1h + k), bv, ac1);
      }
      const int tcol = dir ? (63 - t) : t;
      const float bsum = bihp[gc] + bhhp[gc];
      const bf16* xpc = Xp + (size_t)gc * 2048 + tcol * 32;
#pragma unroll
      for (int r = 0; r < 4; ++r) {
        const int brow = kb * 4 + r;   // D: row=(lane>>4)*4+reg (batch), col=lane&15 (gc)
        gl[gate][lr16][brow] = ac0[r] + b2f(xpc[brow]) + bsum;
        gl[gate][lr16][brow + 16] = ac1[r] + b2f(xpc[brow + 16]) + bsum;
      }
    }
    __syncthreads();
    {
      const int b = tid & 31;
#pragma unroll
      for (int it = 0; it < 2; ++it) {
        const int jl = (tid >> 5) + it * 8;
        const int j = g * 16 + jl;
        const float gi = gl[0][jl][b];
        const float gf = gl[1][jl][b];
        const float gg = gl[2][jl][b];
        const float go = gl[3][jl][b];
        float cn = sigm(gf) * cst[j * 32 + b] + sigm(gi) * tanhf(gg);
        float hn = sigm(go) * tanhf(cn);
        if (dir) {
          const float m = P.mask[b * 64 + (63 - t)];
          hn *= m; cn *= m;
        }
        cst[j * 32 + b] = cn;                  // block-private
        st2p(hbW + (size_t)b * 512 + j, hn);   // plain store -> local L2
      }
    }
    xbar(flg, ep++, g, tid);

    // ---------- Phase B: U (wave 0, j-slice) + attention (waves 1-3, batch g) ----------
    if (wv == 0) {
      // U[b, o-slice] = Wh1[o-slice,:] . h_t[b,:]   (MFMA, K=512)
      const bf16* Brow = Wh1 + (size_t)(g * 16 + lr16) * 512;
      const bf16* A0 = hbW + (size_t)lr16 * 512;
      const bf16* A1 = hbW + (size_t)(lr16 + 16) * 512;
      f32x4 u0 = (f32x4){0.f, 0.f, 0.f, 0.f};
      f32x4 u1 = (f32x4){0.f, 0.f, 0.f, 0.f};
#pragma unroll
      for (int ks = 0; ks < 16; ++ks) {
        const int k = ks * 32 + koff;
        const short8b bv = ldb8(Brow + k);
        u0 = MFMA(ldb8(A0 + k), bv, u0);
        u1 = MFMA(ldb8(A1 + k), bv, u1);
      }
      bf16* Uw = Ubuf + (size_t)t * 32 * 512;
      const int o = g * 16 + lr16;
#pragma unroll
      for (int r = 0; r < 4; ++r) {
        const int b0 = kb * 4 + r;
        st2p(Uw + (size_t)b0 * 512 + o, u0[r]);
        st2p(Uw + (size_t)(b0 + 16) * 512 + o, u1[r]);
      }
    } else if (wv == 1) {
      const short8b v = ldb8(hbW + (size_t)g * 512 + lane * 8);  // h_t[g,:] -> LDS
#pragma unroll
      for (int e = 0; e < 8; ++e) h_lds[lane * 8 + e] = s2f(v[e]);
    }
    __syncthreads();
    if (wv == 1 || wv == 2) {
      const int q = wv - 1;
      const bf16* arow = Af + (size_t)(g * 64 + lane) * 512 + q * 256;
      float part = 0.f;
#pragma unroll 4
      for (int k8 = 0; k8 < 256; k8 += 8) {
        const short8b v = ldb8(arow + k8);
#pragma unroll
        for (int e = 0; e < 8; ++e) part += h_lds[q * 256 + k8 + e] * s2f(v[e]);
      }
      w_part[q][lane] = part;
    }
    __syncthreads();
    if (wv == 3) {
      const float v = (w_part[0][lane] + w_part[1][lane]) * SCALE_F + c0v[g * 64 + lane];
      float mx = v;
#pragma unroll
      for (int d = 1; d < 64; d <<= 1) mx = fmaxf(mx, __shfl_xor(mx, d));
      const float e = expf(v - mx);
      float sm = e;
#pragma unroll
      for (int d = 1; d < 64; d <<= 1) sm += __shfl_xor(sm, d);
      p_lds[lane] = e / sm;
    }
    __syncthreads();
    float a2[2];
#pragma unroll
    for (int it = 0; it < 2; ++it) {           // acc2 = ahb + p . Bm   (all 256 thr)
      const int o = tid + it * 256;
      float acc = ahbp[o];
      const bf16* bmc = Bm + (size_t)(g * 64) * 512 + o;
#pragma unroll 4
      for (int s2 = 0; s2 < 64; ++s2) acc += p_lds[s2] * b2f(bmc[(size_t)s2 * 512]);
      a2[it] = acc;
    }
    xbar(flg, ep++, g, tid);

    // ---------- Phase C: hhat = tanh(U + acc2), batch g ----------
    {
      const bf16* Ur = Ubuf + ((size_t)t * 32 + g) * 512;
#pragma unroll
      for (int it = 0; it < 2; ++it) {
        const int o = tid + it * 256;
        const float hh = tanhf(a2[it] + b2f(Ur[o]));
        st2p(hhW + (size_t)g * 512 + o, hh);                                // plain
        if (dir == 0) {
          P.hcat[(size_t)(g * 64 + t) * 1024 + o] = f2b(hh);                // f_out[:, t]
        } else if (t >= 2) {
          P.hcat[(size_t)(g * 64 + t - 2) * 1024 + 512 + o] = f2b(hh);      // b_shift
        }
      }
      if (t < 63) {                            // prefetch h_t frags for next Phase A
        const bf16* A0 = hbW + (size_t)lr16 * 512;
        const bf16* A1 = hbW + (size_t)(lr16 + 16) * 512;
#pragma unroll
        for (int ks = 0; ks < 16; ++ks) {
          pA0[ks] = ldb8(A0 + ks * 32 + koff);
          pA1[ks] = ldb8(A1 + ks * 32 + koff);
        }
      }
    }
    xbar(flg, ep++, g, tid);
  }
}

// =======================  host  =======================
extern "C" void kernel_launch(void* const* d_in, const int* in_sizes, int n_in,
                              void* d_out, int out_size, void* d_ws, size_t ws_size,
                              hipStream_t stream) {
  (void)in_sizes; (void)n_in; (void)out_size; (void)ws_size;
  const float* src  = (const float*)d_in[0];
  const int*   trg  = (const int*)d_in[1];
  const float* mask = (const float*)d_in[2];
  const float* emb  = (const float*)d_in[3];
  const float* fWih = (const float*)d_in[4];
  const float* fWhh = (const float*)d_in[5];
  const float* fbih = (const float*)d_in[6];
  const float* fbhh = (const float*)d_in[7];
  const float* bWih = (const float*)d_in[8];
  const float* bWhh = (const float*)d_in[9];
  const float* bbih = (const float*)d_in[10];
  const float* bbhh = (const float*)d_in[11];
  const float* fattW = (const float*)d_in[12];
  const float* fattb = (const float*)d_in[13];
  const float* battW = (const float*)d_in[14];
  const float* battb = (const float*)d_in[15];
  const float* fahW = (const float*)d_in[16];
  const float* fahb = (const float*)d_in[17];
  const float* bahW = (const float*)d_in[18];
  const float* bahb = (const float*)d_in[19];
  const float* fcW  = (const float*)d_in[20];
  const float* fcb  = (const float*)d_in[21];
  const float* feed = (const float*)d_in[22];
  const float* hid  = (const float*)d_in[23];

  char* wsp = (char*)d_ws;
  size_t off = 0;
  auto alloc = [&](size_t bytes) -> void* {
    void* p = wsp + off;
    off += (bytes + 255) & ~(size_t)255;
    return p;
  };
  unsigned* claim = (unsigned*)alloc(64);
  unsigned* flags = (unsigned*)alloc((size_t)2 * 192 * 64 * 4);
  bf16* hcat = (bf16*)alloc((size_t)2048 * 1024 * 2);
  const size_t zero_bytes = off;                 // claim + flags + hcat zeroed per launch
  bf16* xg    = (bf16*)alloc((size_t)2048 * 512 * 2);
  bf16* srcb  = (bf16*)alloc((size_t)2048 * 1024 * 2);
  bf16* fcWb  = (bf16*)alloc((size_t)32000 * 1024 * 2);
  bf16* Wxf   = (bf16*)alloc((size_t)2048 * 512 * 2);
  bf16* Wxb   = (bf16*)alloc((size_t)2048 * 512 * 2);
  bf16* Wrecf = (bf16*)alloc((size_t)2048 * 1024 * 2);
  bf16* Wrecb = (bf16*)alloc((size_t)2048 * 1024 * 2);
  bf16* attWtf = (bf16*)alloc((size_t)512 * 1024 * 2);
  bf16* attWtb = (bf16*)alloc((size_t)512 * 1024 * 2);
  bf16* ahW2f = (bf16*)alloc((size_t)512 * 1024 * 2);
  bf16* ahW2b = (bf16*)alloc((size_t)512 * 1024 * 2);
  bf16* Wh1f  = (bf16*)alloc((size_t)512 * 512 * 2);
  bf16* Wh1b  = (bf16*)alloc((size_t)512 * 512 * 2);
  bf16* Xpf   = (bf16*)alloc((size_t)2048 * 2048 * 2);
  bf16* Xpb   = (bf16*)alloc((size_t)2048 * 2048 * 2);
  bf16* Aff   = (bf16*)alloc((size_t)2048 * 512 * 2);
  bf16* Afb   = (bf16*)alloc((size_t)2048 * 512 * 2);
  bf16* Bmf   = (bf16*)alloc((size_t)2048 * 512 * 2);
  bf16* Bmb   = (bf16*)alloc((size_t)2048 * 512 * 2);
  float* c0f  = (float*)alloc(2048 * 4);
  float* c0b  = (float*)alloc(2048 * 4);
  bf16* hh0   = (bf16*)alloc((size_t)65 * 32 * 512 * 2);
  bf16* hh1   = (bf16*)alloc((size_t)65 * 32 * 512 * 2);
  bf16* hb0   = (bf16*)alloc((size_t)65 * 32 * 512 * 2);
  bf16* hb1   = (bf16*)alloc((size_t)65 * 32 * 512 * 2);
  bf16* Uf    = (bf16*)alloc((size_t)64 * 32 * 512 * 2);
  bf16* Ub    = (bf16*)alloc((size_t)64 * 32 * 512 * 2);
  float* cst0 = (float*)alloc((size_t)512 * 32 * 4);
  float* cst1 = (float*)alloc((size_t)512 * 32 * 4);

  hipMemsetAsync(d_ws, 0, zero_bytes, stream);

  k_xg<<<4096, 256, 0, stream>>>(emb, trg, xg);
  k_srcb<<<8192, 256, 0, stream>>>(src, srcb);
  k_fcw<<<8192, 256, 0, stream>>>(fcW, fcWb);
  k_wpack<<<2048, 256, 0, stream>>>(fWih, fWhh, bWih, bWhh, fattW, battW, bahW, fahW,
                                    Wxf, Wxb, Wrecf, Wrecb, attWtf, attWtb, ahW2f, ahW2b,
                                    Wh1f, Wh1b);
  k_c0<<<2048, 256, 0, stream>>>(src, fattb, battb, c0f, c0b);
  k_init<<<64, 256, 0, stream>>>(feed, hid, hh0, hh1, hb0, hb1, cst0, cst1);

  // Xp[gc][r] = (x @ Wih_x^T)^T  (gc-major so scan reads are b-coalesced)
  gemm_k<bf16, false><<<dim3(16, 16), 256, 0, stream>>>(Wxf, xg, Xpf, nullptr, 2048, 2048, 512);
  gemm_k<bf16, false><<<dim3(16, 16), 256, 0, stream>>>(Wxb, xg, Xpb, nullptr, 2048, 2048, 512);
  // A[r][j] = src @ attW ;  Bm[r][o] = src @ ahW_ct^T
  gemm_k<bf16, false><<<dim3(4, 16), 256, 0, stream>>>(srcb, attWtf, Aff, nullptr, 2048, 512, 1024);
  gemm_k<bf16, false><<<dim3(4, 16), 256, 0, stream>>>(srcb, attWtb, Afb, nullptr, 2048, 512, 1024);
  gemm_k<bf16, false><<<dim3(4, 16), 256, 0, stream>>>(srcb, ahW2f, Bmf, nullptr, 2048, 512, 1024);
  gemm_k<bf16, false><<<dim3(4, 16), 256, 0, stream>>>(srcb, ahW2b, Bmb, nullptr, 2048, 512, 1024);

  ScanP sp;
  sp.Wrec[0] = Wrecf; sp.Wrec[1] = Wrecb;
  sp.Xp[0] = Xpf;     sp.Xp[1] = Xpb;
  sp.Af[0] = Aff;     sp.Af[1] = Afb;
  sp.Bm[0] = Bmf;     sp.Bm[1] = Bmb;
  sp.Wh1[0] = Wh1f;   sp.Wh1[1] = Wh1b;
  sp.bih[0] = fbih;   sp.bih[1] = bbih;
  sp.bhh[0] = fbhh;   sp.bhh[1] = bbhh;
  sp.c0[0] = c0f;     sp.c0[1] = c0b;
  sp.ahb[0] = bahb;   sp.ahb[1] = fahb;   // att_hidden weights are swapped in the reference
  sp.mask = mask;
  sp.hh[0] = hh0;     sp.hh[1] = hh1;
  sp.hb[0] = hb0;     sp.hb[1] = hb1;
  sp.U[0] = Uf;       sp.U[1] = Ub;
  sp.cst[0] = cst0;   sp.cst[1] = cst1;
  sp.hcat = hcat;     sp.flags = flags;    sp.claim = claim;
  scan_k<<<1024, 256, 0, stream>>>(sp);

  // logits[b*64+t][v] = hcat @ fcW^T + fcb
  gemm_k<float, true><<<dim3(250, 16), 256, 0, stream>>>(hcat, fcWb, (float*)d_out, fcb,
                                                         2048, 32000, 1024);
}

// Round 8
// 2866.891 us; speedup vs baseline: 1.7764x; 1.0087x over previous
//
#include <hip/hip_runtime.h>
#include <hip/hip_bf16.h>
#include <math.h>

typedef __hip_bfloat16 bf16;
typedef __attribute__((ext_vector_type(8))) short short8b;
typedef __attribute__((ext_vector_type(8))) __bf16 bf16x8;
typedef __attribute__((ext_vector_type(4))) float f32x4;

#define SCALE_F 0.04419417382415922f  // 1/sqrt(512)

// ---- MFMA wrapper tolerant of either builtin signature (v8i16 or v8bf16) ----
template <typename V>
static __device__ inline auto mfma_try(V a, V b, f32x4 c, int)
    -> decltype(__builtin_amdgcn_mfma_f32_16x16x32_bf16(a, b, c, 0, 0, 0)) {
  return __builtin_amdgcn_mfma_f32_16x16x32_bf16(a, b, c, 0, 0, 0);
}
template <typename V>
static __device__ inline auto mfma_try(V a, V b, f32x4 c, long)
    -> decltype(__builtin_amdgcn_mfma_f32_16x16x32_bf16(
        __builtin_bit_cast(bf16x8, a), __builtin_bit_cast(bf16x8, b), c, 0, 0, 0)) {
  return __builtin_amdgcn_mfma_f32_16x16x32_bf16(
      __builtin_bit_cast(bf16x8, a), __builtin_bit_cast(bf16x8, b), c, 0, 0, 0);
}
static __device__ inline f32x4 MFMA(short8b a, short8b b, f32x4 c) {
  return mfma_try(a, b, c, 0);
}

static __device__ inline short8b ldb8(const bf16* p) {
  return *reinterpret_cast<const short8b*>(p);
}
static __device__ inline float b2f(bf16 v) { return __bfloat162float(v); }
static __device__ inline bf16 f2b(float v) { return __float2bfloat16(v); }
static __device__ inline float s2f(short s) {
  unsigned u = ((unsigned)(unsigned short)s) << 16;
  return __builtin_bit_cast(float, u);
}
static __device__ inline unsigned pack2(float lo, float hi) {
  const unsigned a = (unsigned)__builtin_bit_cast(unsigned short, f2b(lo));
  const unsigned b = (unsigned)__builtin_bit_cast(unsigned short, f2b(hi));
  return a | (b << 16);
}
static __device__ inline float sigm(float x) { return 1.f / (1.f + expf(-x)); }

// write-through stores: bypass L1/L2, land at the LLC (device coherence
// point) -> cross-XCD visible without cache-wide fence ops. (R4-proven.)
static __device__ inline void st2_wt(bf16* p, float v) {
  unsigned ud = (unsigned)__builtin_bit_cast(unsigned short, f2b(v));
  asm volatile("global_store_short %0, %1, off sc0 sc1" ::"v"(p), "v"(ud)
               : "memory");
}
static __device__ inline void st4_wt(bf16* p, float lo, float hi) {
  unsigned ud = pack2(lo, hi);
  asm volatile("global_store_dword %0, %1, off sc0 sc1" ::"v"(p), "v"(ud)
               : "memory");
}

static __device__ inline void st_flag(unsigned* p, unsigned v) {
  asm volatile("global_store_dword %0, %1, off sc0 sc1" ::"v"(p), "v"(v)
               : "memory");
}
static __device__ inline unsigned ld_flag(const unsigned* p) {
  unsigned v;
  asm volatile("global_load_dword %0, %1, off sc0 sc1\n\ts_waitcnt vmcnt(0)"
               : "=v"(v)
               : "v"(p)
               : "memory");
  return v;
}

// ---- contention-free LLC flag barrier (R4-proven) ----
static __device__ inline void gbar(unsigned* flags, unsigned ep, int blk, int tid) {
  asm volatile("s_waitcnt vmcnt(0)" ::: "memory");
  __syncthreads();
  if (tid < 64) {
    unsigned* row = flags + (size_t)ep * 64;
    if (tid == 0) st_flag(row + blk, 1u);
    while (true) {
      const unsigned v = ld_flag(row + tid);
      if (__ballot(v != 0) == ~0ull) break;
      __builtin_amdgcn_s_sleep(1);
    }
  }
  __syncthreads();
}

// =======================  generic MFMA GEMM  =======================
// C[M,N] = A[M,K] @ B[N,K]^T (+bias), A/B bf16 row-major K-contig, fp32 accum.
template <typename OutT, bool HAS_BIAS>
__global__ __launch_bounds__(256) void gemm_k(
    const bf16* __restrict__ A, const bf16* __restrict__ Bw,
    OutT* __restrict__ C, const float* __restrict__ bias,
    int M, int N, int K) {
  const int lane = threadIdx.x & 63;
  const int wid = threadIdx.x >> 6;
  const int m0 = blockIdx.y * 128 + (wid >> 1) * 64;
  const int n0 = blockIdx.x * 128 + (wid & 1) * 64;
  const int lr = lane & 15;
  const int lk = (lane >> 4) * 8;
  f32x4 acc[4][4];
#pragma unroll
  for (int i = 0; i < 4; ++i)
#pragma unroll
    for (int j = 0; j < 4; ++j) acc[i][j] = (f32x4){0.f, 0.f, 0.f, 0.f};
  const bf16* Ap = A + (size_t)(m0 + lr) * K + lk;
  const bf16* Bp = Bw + (size_t)(n0 + lr) * K + lk;
  for (int k0 = 0; k0 < K; k0 += 32) {
    short8b av[4], bv[4];
#pragma unroll
    for (int i = 0; i < 4; ++i) av[i] = ldb8(Ap + (size_t)i * 16 * K + k0);
#pragma unroll
    for (int i = 0; i < 4; ++i) bv[i] = ldb8(Bp + (size_t)i * 16 * K + k0);
#pragma unroll
    for (int mi = 0; mi < 4; ++mi)
#pragma unroll
      for (int ni = 0; ni < 4; ++ni)
        acc[mi][ni] = MFMA(av[mi], bv[ni], acc[mi][ni]);
  }
  const int rb = (lane >> 4) * 4;
#pragma unroll
  for (int mi = 0; mi < 4; ++mi) {
#pragma unroll
    for (int r = 0; r < 4; ++r) {
      const int row = m0 + mi * 16 + rb + r;
#pragma unroll
      for (int ni = 0; ni < 4; ++ni) {
        const int col = n0 + ni * 16 + lr;
        float v = acc[mi][ni][r];
        if (HAS_BIAS) v += bias[col];
        if constexpr (sizeof(OutT) == 2) {
          C[(size_t)row * N + col] = f2b(v);
        } else {
          C[(size_t)row * N + col] = v;
        }
      }
    }
  }
}

// =======================  prep kernels  =======================
__global__ void k_xg(const float* __restrict__ emb, const int* __restrict__ trg,
                     bf16* __restrict__ xg) {
  const int i = blockIdx.x * 256 + threadIdx.x;   // 2048*512 exact
  const int r = i >> 9, e = i & 511;
  const int t = r >> 5, b = r & 31;
  const int tok = trg[b * 64 + t];
  xg[i] = f2b(emb[(size_t)tok * 512 + e]);
}

__global__ void k_srcb(const float* __restrict__ s, bf16* __restrict__ d) {
  const int i = blockIdx.x * 256 + threadIdx.x;   // 2048*1024 exact
  d[i] = f2b(s[i]);
}

__global__ void k_fcw(const float* __restrict__ s, bf16* __restrict__ d) {
  const size_t stride = (size_t)gridDim.x * blockDim.x;
  for (size_t i = blockIdx.x * (size_t)blockDim.x + threadIdx.x;
       i < (size_t)32000 * 1024; i += stride)
    d[i] = f2b(s[i]);
}

// Bm[b*64+s][o] -> Bmt[b][o][s]  (dense s-contiguous rows for the a2 dot)
__global__ void k_bmt(const bf16* __restrict__ in, bf16* __restrict__ out) {
  const int i = blockIdx.x * 256 + threadIdx.x;   // 32*512*64 = 1048576 exact
  const int b = i >> 15, rem = i & 32767, o = rem >> 6, s = rem & 63;
  out[i] = in[(size_t)(b * 64 + s) * 512 + o];
}

__global__ void k_wpack(const float* __restrict__ fWih, const float* __restrict__ fWhh,
                        const float* __restrict__ bWih, const float* __restrict__ bWhh,
                        const float* __restrict__ fattW, const float* __restrict__ battW,
                        const float* __restrict__ bahW, const float* __restrict__ fahW,
                        bf16* Wxf, bf16* Wxb, bf16* Wrecf, bf16* Wrecb,
                        bf16* attWtf, bf16* attWtb, bf16* ahW2f, bf16* ahW2b,
                        bf16* Wh1f, bf16* Wh1b) {
  const int stride = gridDim.x * blockDim.x;
  const int i0 = blockIdx.x * blockDim.x + threadIdx.x;
  for (int i = i0; i < 2048 * 512; i += stride) {        // Wih x-slice
    const int gc = i >> 9, k = i & 511;
    Wxf[i] = f2b(fWih[(size_t)gc * 1024 + k]);
    Wxb[i] = f2b(bWih[(size_t)gc * 1024 + k]);
  }
  for (int i = i0; i < 2048 * 1024; i += stride) {       // [Wih_h | Whh]
    const int gc = i >> 10, k = i & 1023;
    float vf, vb;
    if (k < 512) { vf = fWih[(size_t)gc * 1024 + 512 + k]; vb = bWih[(size_t)gc * 1024 + 512 + k]; }
    else         { vf = fWhh[(size_t)gc * 512 + k - 512]; vb = bWhh[(size_t)gc * 512 + k - 512]; }
    Wrecf[i] = f2b(vf); Wrecb[i] = f2b(vb);
  }
  for (int i = i0; i < 512 * 1024; i += stride) {        // attW transpose
    const int j = i >> 10, d = i & 1023;
    attWtf[i] = f2b(fattW[(size_t)d * 512 + j]);
    attWtb[i] = f2b(battW[(size_t)d * 512 + j]);
  }
  for (int i = i0; i < 512 * 1024; i += stride) {        // ah_W ct-slice (swapped: fwd uses bah)
    const int o = i >> 10, d = i & 1023;
    ahW2f[i] = f2b(bahW[(size_t)o * 1536 + 512 + d]);
    ahW2b[i] = f2b(fahW[(size_t)o * 1536 + 512 + d]);
  }
  for (int i = i0; i < 512 * 512; i += stride) {         // ah_W h-slice bf16 [o][k]
    const int o = i >> 9, k = i & 511;
    Wh1f[i] = f2b(bahW[(size_t)o * 1536 + k]);
    Wh1b[i] = f2b(fahW[(size_t)o * 1536 + k]);
  }
}

__global__ void k_c0(const float* __restrict__ src, const float* __restrict__ fb,
                     const float* __restrict__ bb, float* __restrict__ c0f,
                     float* __restrict__ c0b) {
  const int r = blockIdx.x;
  const int tid = threadIdx.x;
  float pf = 0.f, pb = 0.f;
  for (int d = tid; d < 1024; d += 256) {
    const float s = src[(size_t)r * 1024 + d];
    pf += s * fb[d];
    pb += s * bb[d];
  }
#pragma unroll
  for (int d = 1; d < 64; d <<= 1) { pf += __shfl_xor(pf, d); pb += __shfl_xor(pb, d); }
  __shared__ float rf[4], rb2[4];
  if ((tid & 63) == 0) { rf[tid >> 6] = pf; rb2[tid >> 6] = pb; }
  __syncthreads();
  if (tid == 0) {
    c0f[r] = (rf[0] + rf[1] + rf[2] + rf[3]) * SCALE_F;
    c0b[r] = (rb2[0] + rb2[1] + rb2[2] + rb2[3]) * SCALE_F;
  }
}

// rolling state buffers per dir: hh[65][32][512], hb[65][32][512] bf16
__global__ void k_init(const float* __restrict__ feed, const float* __restrict__ hid,
                       bf16* hh0, bf16* hh1, bf16* hb0, bf16* hb1,
                       float* cst0, float* cst1) {
  const int i = blockIdx.x * 256 + threadIdx.x;   // 32*512 exact
  const int b = i >> 9, k = i & 511;
  hh0[i] = f2b(feed[k]);
  hh1[i] = f2b(feed[512 + k]);
  hb0[i] = f2b(hid[k]);
  hb1[i] = f2b(hid[1024 + k]);
  cst0[k * 32 + b] = hid[512 + k];
  cst1[k * 32 + b] = hid[1536 + k];
}

// =======================  sequential scan  =======================
struct ScanP {
  const bf16* Wrec[2]; const bf16* Xp[2]; const bf16* Af[2]; const bf16* Bmt[2];
  const bf16* Wh1[2]; const float* bih[2]; const float* bhh[2];
  const float* c0[2]; const float* ahb[2]; const float* mask;
  bf16* hh[2]; bf16* hb[2]; bf16* U[2]; float* cst[2]; bf16* hcat; unsigned* flags;
};

__global__ __launch_bounds__(256) void scan_k(ScanP P) {
  const int blk = blockIdx.x;     // 64 blocks
  const int dir = blk >> 5;       // 0 fwd, 1 bwd
  const int g = blk & 31;         // PhaseA/B1: j-slice; PhaseB2/C: batch index
  const int tid = threadIdx.x;
  const int lane = tid & 63;
  const int wv = tid >> 6;

  const bf16* __restrict__ Wrec = P.Wrec[dir];
  const bf16* __restrict__ Xp = P.Xp[dir];
  const bf16* __restrict__ Af = P.Af[dir];
  const bf16* __restrict__ Bmt = P.Bmt[dir];
  const bf16* __restrict__ Wh1 = P.Wh1[dir];
  const float* __restrict__ bihp = P.bih[dir];
  const float* __restrict__ bhhp = P.bhh[dir];
  const float* __restrict__ c0v = P.c0[dir];
  const float* __restrict__ ahbp = P.ahb[dir];
  bf16* __restrict__ hhB = P.hh[dir];
  bf16* __restrict__ hbB = P.hb[dir];
  bf16* __restrict__ Ubuf = P.U[dir];
  float* __restrict__ cst = P.cst[dir];

  __shared__ float gl[4][16][33];
  __shared__ float h_lds[512];
  __shared__ float w_part[2][64];
  __shared__ float p_lds[64];

  unsigned ep = 0;
  const int lr16 = lane & 15;
  const int kb = lane >> 4;
  const int koff = kb * 8;

  // prefetched h_{t-1} A-fragments (rows lr16, lr16+16), registers
  short8b pA0[16], pA1[16];
  {
    const bf16* A0 = hbB + (size_t)lr16 * 512;           // slot 0 = h_{-1}
    const bf16* A1 = hbB + (size_t)(lr16 + 16) * 512;
#pragma unroll
    for (int ks = 0; ks < 16; ++ks) {
      pA0[ks] = ldb8(A0 + ks * 32 + koff);
      pA1[ks] = ldb8(A1 + ks * 32 + koff);
    }
  }

  for (int t = 0; t < 64; ++t) {
    const bf16* hhR = hhB + (size_t)t * 32 * 512;        // hhat_{t-1}
    bf16* hhW = hhB + (size_t)(t + 1) * 32 * 512;
    bf16* hbW = hbB + (size_t)(t + 1) * 32 * 512;        // h_t (written below)

    // ---------- Phase A: gates (MFMA) + LSTM cell, block owns j-slice ----------
    {
      const int gate = wv;                   // wave 0..3 -> i,f,g,o
      const int gc = gate * 512 + g * 16 + lr16;
      const bf16* Brow = Wrec + (size_t)gc * 1024;
      const bf16* A0h = hhR + (size_t)lr16 * 512;
      const bf16* A1h = hhR + (size_t)(lr16 + 16) * 512;
      f32x4 ac0 = (f32x4){0.f, 0.f, 0.f, 0.f};
      f32x4 ac1 = (f32x4){0.f, 0.f, 0.f, 0.f};
#pragma unroll
      for (int ks = 0; ks < 16; ++ks) {      // h part (prefetched regs)
        const int k = ks * 32 + koff;
        const short8b bv = ldb8(Brow + 512 + k);
        ac0 = MFMA(pA0[ks], bv, ac0);
        ac1 = MFMA(pA1[ks], bv, ac1);
      }
      // hhat part: stage loads in 2 chunks of 8 so 16 loads are in flight
#pragma unroll
      for (int c = 0; c < 2; ++c) {
        short8b sa[8], sb[8];
#pragma unroll
        for (int i = 0; i < 8; ++i) {
          const int k = (c * 8 + i) * 32 + koff;
          sa[i] = ldb8(A0h + k);
          sb[i] = ldb8(A1h + k);
        }
#pragma unroll
        for (int i = 0; i < 8; ++i) {
          const int k = (c * 8 + i) * 32 + koff;
          const short8b bv = ldb8(Brow + k);
          ac0 = MFMA(sa[i], bv, ac0);
          ac1 = MFMA(sb[i], bv, ac1);
        }
      }
      const int tcol = dir ? (63 - t) : t;
      const float bsum = bihp[gc] + bhhp[gc];
      const bf16* xpc = Xp + (size_t)gc * 2048 + tcol * 32;
#pragma unroll
      for (int r = 0; r < 4; ++r) {
        const int brow = kb * 4 + r;   // D: row=(lane>>4)*4+reg (batch), col=lane&15 (gc)
        gl[gate][lr16][brow] = ac0[r] + b2f(xpc[brow]) + bsum;
        gl[gate][lr16][brow + 16] = ac1[r] + b2f(xpc[brow + 16]) + bsum;
      }
    }
    __syncthreads();
    {
      const int b = tid & 31;
      const int jp = (tid >> 5) * 2;         // 0,2,..,14: two consecutive j per thread
      float hn2[2];
#pragma unroll
      for (int u = 0; u < 2; ++u) {
        const int jl = jp + u;
        const int j = g * 16 + jl;
        const float gi = gl[0][jl][b];
        const float gf = gl[1][jl][b];
        const float gg = gl[2][jl][b];
        const float go = gl[3][jl][b];
        float cn = sigm(gf) * cst[j * 32 + b] + sigm(gi) * tanhf(gg);
        float hn = sigm(go) * tanhf(cn);
        if (dir) {
          const float m = P.mask[b * 64 + (63 - t)];
          hn *= m; cn *= m;
        }
        cst[j * 32 + b] = cn;                               // block-private
        hn2[u] = hn;
      }
      st4_wt(hbW + (size_t)b * 512 + g * 16 + jp, hn2[0], hn2[1]);
    }
    gbar(P.flags, ep++, blk, tid);

    // ---------- Phase B: U (wave 0, j-slice) + attention (waves 1-3, batch g) ----------
    if (wv == 0) {
      // U[b, o-slice] = Wh1[o-slice,:] . h_t[b,:]   (MFMA, K=512)
      const bf16* Brow = Wh1 + (size_t)(g * 16 + lr16) * 512;
      const bf16* A0 = hbW + (size_t)lr16 * 512;
      const bf16* A1 = hbW + (size_t)(lr16 + 16) * 512;
      f32x4 u0 = (f32x4){0.f, 0.f, 0.f, 0.f};
      f32x4 u1 = (f32x4){0.f, 0.f, 0.f, 0.f};
#pragma unroll
      for (int ks = 0; ks < 16; ++ks) {
        const int k = ks * 32 + koff;
        const short8b bv = ldb8(Brow + k);
        u0 = MFMA(ldb8(A0 + k), bv, u0);
        u1 = MFMA(ldb8(A1 + k), bv, u1);
      }
      bf16* Uw = Ubuf + (size_t)t * 32 * 512;
      const int o = g * 16 + lr16;
#pragma unroll
      for (int r = 0; r < 4; ++r) {
        const int b0 = kb * 4 + r;
        st2_wt(Uw + (size_t)b0 * 512 + o, u0[r]);
        st2_wt(Uw + (size_t)(b0 + 16) * 512 + o, u1[r]);
      }
    } else if (wv == 1) {
      const short8b v = ldb8(hbW + (size_t)g * 512 + lane * 8);  // h_t[g,:] -> LDS
#pragma unroll
      for (int e = 0; e < 8; ++e) h_lds[lane * 8 + e] = s2f(v[e]);
    }
    __syncthreads();
    if (wv == 1 || wv == 2) {
      const int q = wv - 1;
      const bf16* arow = Af + (size_t)(g * 64 + lane) * 512 + q * 256;
      float part = 0.f;
#pragma unroll 8
      for (int k8 = 0; k8 < 256; k8 += 8) {
        const short8b v = ldb8(arow + k8);
#pragma unroll
        for (int e = 0; e < 8; ++e) part += h_lds[q * 256 + k8 + e] * s2f(v[e]);
      }
      w_part[q][lane] = part;
    }
    __syncthreads();
    if (wv == 3) {
      const float v = (w_part[0][lane] + w_part[1][lane]) * SCALE_F + c0v[g * 64 + lane];
      float mx = v;
#pragma unroll
      for (int d = 1; d < 64; d <<= 1) mx = fmaxf(mx, __shfl_xor(mx, d));
      const float e = expf(v - mx);
      float sm = e;
#pragma unroll
      for (int d = 1; d < 64; d <<= 1) sm += __shfl_xor(sm, d);
      p_lds[lane] = e / sm;
    }
    __syncthreads();
    // acc2 = ahb + p . Bm : thread owns o-pair (2*tid, 2*tid+1); Bmt rows are
    // s-contiguous -> 16 dense independent 16B loads, one latency round trip.
    float a2[2];
    {
      const int o2 = tid * 2;
      const bf16* bm0 = Bmt + ((size_t)g * 512 + o2) * 64;
      short8b v0[8], v1[8];
#pragma unroll
      for (int i = 0; i < 8; ++i) {
        v0[i] = ldb8(bm0 + i * 8);
        v1[i] = ldb8(bm0 + 64 + i * 8);
      }
      float s0 = ahbp[o2], s1 = ahbp[o2 + 1];
#pragma unroll
      for (int i = 0; i < 8; ++i)
#pragma unroll
        for (int e = 0; e < 8; ++e) {
          const float p = p_lds[i * 8 + e];
          s0 += p * s2f(v0[i][e]);
          s1 += p * s2f(v1[i][e]);
        }
      a2[0] = s0; a2[1] = s1;
    }
    gbar(P.flags, ep++, blk, tid);

    // ---------- Phase C: hhat = tanh(U + acc2), batch g ----------
    {
      const int o2 = tid * 2;
      const unsigned uu =
          *reinterpret_cast<const unsigned*>(Ubuf + ((size_t)t * 32 + g) * 512 + o2);
      const float h0 = tanhf(a2[0] + s2f((short)(uu & 0xffffu)));
      const float h1 = tanhf(a2[1] + s2f((short)(uu >> 16)));
      st4_wt(hhW + (size_t)g * 512 + o2, h0, h1);
      const unsigned hp = pack2(h0, h1);
      if (dir == 0) {
        *reinterpret_cast<unsigned*>(P.hcat + (size_t)(g * 64 + t) * 1024 + o2) = hp;
      } else if (t >= 2) {
        *reinterpret_cast<unsigned*>(P.hcat + (size_t)(g * 64 + t - 2) * 1024 + 512 + o2) = hp;
      }
      if (t < 63) {                            // prefetch h_t frags for next Phase A
        const bf16* A0 = hbW + (size_t)lr16 * 512;
        const bf16* A1 = hbW + (size_t)(lr16 + 16) * 512;
#pragma unroll
        for (int ks = 0; ks < 16; ++ks) {
          pA0[ks] = ldb8(A0 + ks * 32 + koff);
          pA1[ks] = ldb8(A1 + ks * 32 + koff);
        }
      }
    }
    gbar(P.flags, ep++, blk, tid);
  }
}

// =======================  host  =======================
extern "C" void kernel_launch(void* const* d_in, const int* in_sizes, int n_in,
                              void* d_out, int out_size, void* d_ws, size_t ws_size,
                              hipStream_t stream) {
  (void)in_sizes; (void)n_in; (void)out_size; (void)ws_size;
  const float* src  = (const float*)d_in[0];
  const int*   trg  = (const int*)d_in[1];
  const float* mask = (const float*)d_in[2];
  const float* emb  = (const float*)d_in[3];
  const float* fWih = (const float*)d_in[4];
  const float* fWhh = (const float*)d_in[5];
  const float* fbih = (const float*)d_in[6];
  const float* fbhh = (const float*)d_in[7];
  const float* bWih = (const float*)d_in[8];
  const float* bWhh = (const float*)d_in[9];
  const float* bbih = (const float*)d_in[10];
  const float* bbhh = (const float*)d_in[11];
  const float* fattW = (const float*)d_in[12];
  const float* fattb = (const float*)d_in[13];
  const float* battW = (const float*)d_in[14];
  const float* battb = (const float*)d_in[15];
  const float* fahW = (const float*)d_in[16];
  const float* fahb = (const float*)d_in[17];
  const float* bahW = (const float*)d_in[18];
  const float* bahb = (const float*)d_in[19];
  const float* fcW  = (const float*)d_in[20];
  const float* fcb  = (const float*)d_in[21];
  const float* feed = (const float*)d_in[22];
  const float* hid  = (const float*)d_in[23];

  char* wsp = (char*)d_ws;
  size_t off = 0;
  auto alloc = [&](size_t bytes) -> void* {
    void* p = wsp + off;
    off += (bytes + 255) & ~(size_t)255;
    return p;
  };
  unsigned* flags = (unsigned*)alloc((size_t)192 * 64 * 4);
  bf16* hcat = (bf16*)alloc((size_t)2048 * 1024 * 2);
  const size_t zero_bytes = off;                 // flags + hcat zeroed per launch
  bf16* xg    = (bf16*)alloc((size_t)2048 * 512 * 2);
  bf16* srcb  = (bf16*)alloc((size_t)2048 * 1024 * 2);
  bf16* fcWb  = (bf16*)alloc((size_t)32000 * 1024 * 2);
  bf16* Wxf   = (bf16*)alloc((size_t)2048 * 512 * 2);
  bf16* Wxb   = (bf16*)alloc((size_t)2048 * 512 * 2);
  bf16* Wrecf = (bf16*)alloc((size_t)2048 * 1024 * 2);
  bf16* Wrecb = (bf16*)alloc((size_t)2048 * 1024 * 2);
  bf16* attWtf = (bf16*)alloc((size_t)512 * 1024 * 2);
  bf16* attWtb = (bf16*)alloc((size_t)512 * 1024 * 2);
  bf16* ahW2f = (bf16*)alloc((size_t)512 * 1024 * 2);
  bf16* ahW2b = (bf16*)alloc((size_t)512 * 1024 * 2);
  bf16* Wh1f  = (bf16*)alloc((size_t)512 * 512 * 2);
  bf16* Wh1b  = (bf16*)alloc((size_t)512 * 512 * 2);
  bf16* Xpf   = (bf16*)alloc((size_t)2048 * 2048 * 2);
  bf16* Xpb   = (bf16*)alloc((size_t)2048 * 2048 * 2);
  bf16* Aff   = (bf16*)alloc((size_t)2048 * 512 * 2);
  bf16* Afb   = (bf16*)alloc((size_t)2048 * 512 * 2);
  bf16* Bmf   = (bf16*)alloc((size_t)2048 * 512 * 2);
  bf16* Bmb   = (bf16*)alloc((size_t)2048 * 512 * 2);
  bf16* Bmtf  = (bf16*)alloc((size_t)2048 * 512 * 2);
  bf16* Bmtb  = (bf16*)alloc((size_t)2048 * 512 * 2);
  float* c0f  = (float*)alloc(2048 * 4);
  float* c0b  = (float*)alloc(2048 * 4);
  bf16* hh0   = (bf16*)alloc((size_t)65 * 32 * 512 * 2);
  bf16* hh1   = (bf16*)alloc((size_t)65 * 32 * 512 * 2);
  bf16* hb0   = (bf16*)alloc((size_t)65 * 32 * 512 * 2);
  bf16* hb1   = (bf16*)alloc((size_t)65 * 32 * 512 * 2);
  bf16* Uf    = (bf16*)alloc((size_t)64 * 32 * 512 * 2);
  bf16* Ub    = (bf16*)alloc((size_t)64 * 32 * 512 * 2);
  float* cst0 = (float*)alloc((size_t)512 * 32 * 4);
  float* cst1 = (float*)alloc((size_t)512 * 32 * 4);

  hipMemsetAsync(d_ws, 0, zero_bytes, stream);

  k_xg<<<4096, 256, 0, stream>>>(emb, trg, xg);
  k_srcb<<<8192, 256, 0, stream>>>(src, srcb);
  k_fcw<<<8192, 256, 0, stream>>>(fcW, fcWb);
  k_wpack<<<2048, 256, 0, stream>>>(fWih, fWhh, bWih, bWhh, fattW, battW, bahW, fahW,
                                    Wxf, Wxb, Wrecf, Wrecb, attWtf, attWtb, ahW2f, ahW2b,
                                    Wh1f, Wh1b);
  k_c0<<<2048, 256, 0, stream>>>(src, fattb, battb, c0f, c0b);
  k_init<<<64, 256, 0, stream>>>(feed, hid, hh0, hh1, hb0, hb1, cst0, cst1);

  // Xp[gc][r] = (x @ Wih_x^T)^T  (gc-major so scan reads are b-coalesced)
  gemm_k<bf16, false><<<dim3(16, 16), 256, 0, stream>>>(Wxf, xg, Xpf, nullptr, 2048, 2048, 512);
  gemm_k<bf16, false><<<dim3(16, 16), 256, 0, stream>>>(Wxb, xg, Xpb, nullptr, 2048, 2048, 512);
  // A[r][j] = src @ attW ;  Bm[r][o] = src @ ahW_ct^T
  gemm_k<bf16, false><<<dim3(4, 16), 256, 0, stream>>>(srcb, attWtf, Aff, nullptr, 2048, 512, 1024);
  gemm_k<bf16, false><<<dim3(4, 16), 256, 0, stream>>>(srcb, attWtb, Afb, nullptr, 2048, 512, 1024);
  gemm_k<bf16, false><<<dim3(4, 16), 256, 0, stream>>>(srcb, ahW2f, Bmf, nullptr, 2048, 512, 1024);
  gemm_k<bf16, false><<<dim3(4, 16), 256, 0, stream>>>(srcb, ahW2b, Bmb, nullptr, 2048, 512, 1024);
  k_bmt<<<4096, 256, 0, stream>>>(Bmf, Bmtf);
  k_bmt<<<4096, 256, 0, stream>>>(Bmb, Bmtb);

  ScanP sp;
  sp.Wrec[0] = Wrecf; sp.Wrec[1] = Wrecb;
  sp.Xp[0] = Xpf;     sp.Xp[1] = Xpb;
  sp.Af[0] = Aff;     sp.Af[1] = Afb;
  sp.Bmt[0] = Bmtf;   sp.Bmt[1] = Bmtb;
  sp.Wh1[0] = Wh1f;   sp.Wh1[1] = Wh1b;
  sp.bih[0] = fbih;   sp.bih[1] = bbih;
  sp.bhh[0] = fbhh;   sp.bhh[1] = bbhh;
  sp.c0[0] = c0f;     sp.c0[1] = c0b;
  sp.ahb[0] = bahb;   sp.ahb[1] = fahb;   // att_hidden weights are swapped in the reference
  sp.mask = mask;
  sp.hh[0] = hh0;     sp.hh[1] = hh1;
  sp.hb[0] = hb0;     sp.hb[1] = hb1;
  sp.U[0] = Uf;       sp.U[1] = Ub;
  sp.cst[0] = cst0;   sp.cst[1] = cst1;
  sp.hcat = hcat;     sp.flags = flags;
  scan_k<<<64, 256, 0, stream>>>(sp);

  // logits[b*64+t][v] = hcat @ fcW^T + fcb
  gemm_k<float, true><<<dim3(250, 16), 256, 0, stream>>>(hcat, fcWb, (float*)d_out, fcb,
                                                         2048, 32000, 1024);
}